// Round 1
// baseline (174.553 us; speedup 1.0000x reference)
//
#include <hip/hip_runtime.h>
#include <hip/hip_bf16.h>

// B=4, C=128, H=W=64 -> N=4096. ALL I/O FP32.
// Round 6: LDS-BW attack.
//  - swapped QK^T (mfma(K,Q)) -> P lane-local; cvt_pk_bf16 + permlane32_swap
//    build PV B-frags in-register (P LDS round-trip + La-MFMA removed).
//  - each wave: 2 q-sets x 32 rows x 64 channels -> every kf/vf LDS read
//    feeds 2 MFMAs (halves LDS bytes/MFMA; LDS-BW was the measured ceiling).
//  - O^T = mfma(V^T, P^T): l is lane-local, out/Op stores coalesced (lane=n).
//  - double-buffered K/V, raw s_barrier + counted s_waitcnt vmcnt(8) prefetch.
//  - SPLIT=4 (512 blocks = 2/CU at 64KB LDS), halves partial traffic.

#define BATCH 4
#define CH    128
#define NTOK  4096
#define TK    64
#define SCALE 0.08838834764831845f   // 1/sqrt(128)
#define LOG2E 1.4426950408889634f
#define MFIX  16.0f                  // fixed softmax offset (log2 units)

typedef __attribute__((ext_vector_type(8)))  short short8;
typedef __attribute__((ext_vector_type(4)))  float f32x4;
typedef __attribute__((ext_vector_type(16))) float f32x16;

static __device__ __forceinline__ unsigned short f2bf(float f) {
    __hip_bfloat16 h = (__hip_bfloat16)f;
    return *(const unsigned short*)&h;
}

static __device__ __forceinline__ unsigned cvt_pk_bf16(float lo, float hi) {
    unsigned r;
    asm("v_cvt_pk_bf16_f32 %0, %1, %2" : "=v"(r) : "v"(lo), "v"(hi));
    return r;
}

// ---------------- W fp32 -> bf16 ----------------
__global__ __launch_bounds__(256) void convert_w_kernel(
    const float* __restrict__ Wq, const float* __restrict__ Wk,
    const float* __restrict__ Wv, unsigned short* __restrict__ wb)
{
    const int idx = (blockIdx.x * 256 + threadIdx.x) * 4;
    const float* srcs[3] = {Wq, Wk, Wv};
    #pragma unroll
    for (int m = 0; m < 3; ++m) {
        float4 v = *(const float4*)(srcs[m] + idx);
        unsigned short o[4] = {f2bf(v.x), f2bf(v.y), f2bf(v.z), f2bf(v.w)};
        *(uint2*)(wb + (size_t)m * CH * CH + idx) = *(const uint2*)o;
    }
}

// ---------------- MFMA QKV projection (unchanged, proven) ----------------
__global__ __launch_bounds__(256) void proj_mfma_kernel(
    const float* __restrict__ x,
    const unsigned short* __restrict__ wqb, const unsigned short* __restrict__ wkb,
    const unsigned short* __restrict__ wvb,
    const float* __restrict__ bq, const float* __restrict__ bk,
    const float* __restrict__ bv,
    unsigned short* __restrict__ q_ws, unsigned short* __restrict__ k_ws,
    unsigned short* __restrict__ vt_ws)
{
    __shared__ __align__(16) unsigned short XsT[64 * CH];  // 16 KB, swizzled

    const int t    = threadIdx.x;
    const int w    = t >> 6;
    const int lane = t & 63;
    const int quad = lane >> 4;
    const int c16  = lane & 15;
    const int n0   = blockIdx.x * 64;
    const int b    = blockIdx.y;
    const float* xb = x + (size_t)b * CH * NTOK;

    {
        const int tok = lane;
        #pragma unroll
        for (int cc = 0; cc < 4; ++cc) {
            const int cb = 32 * w + 8 * cc;
            unsigned short tmp[8];
            #pragma unroll
            for (int j = 0; j < 8; ++j)
                tmp[j] = f2bf(xb[(size_t)(cb + j) * NTOK + n0 + tok]);
            const int phys = ((cb >> 3) ^ (tok & 15));
            *(short8*)&XsT[tok * CH + phys * 8] = *(const short8*)tmp;
        }
    }
    __syncthreads();

    short8 xa[4];
    #pragma unroll
    for (int ks = 0; ks < 4; ++ks)
        xa[ks] = *(const short8*)&XsT[(16 * w + c16) * CH + (((4 * ks + quad) ^ c16) << 3)];

    // ---- Q/K ----
    #pragma unroll
    for (int nt = 0; nt < 8; ++nt) {
        f32x4 aq = (f32x4){0.f, 0.f, 0.f, 0.f};
        f32x4 ak = (f32x4){0.f, 0.f, 0.f, 0.f};
        const unsigned short* wqr = wqb + (16 * nt + c16) * CH;
        const unsigned short* wkr = wkb + (16 * nt + c16) * CH;
        #pragma unroll
        for (int ks = 0; ks < 4; ++ks) {
            const short8 bqf = *(const short8*)(wqr + 32 * ks + 8 * quad);
            const short8 bkf = *(const short8*)(wkr + 32 * ks + 8 * quad);
            aq = __builtin_amdgcn_mfma_f32_16x16x32_bf16(xa[ks], bqf, aq, 0, 0, 0);
            ak = __builtin_amdgcn_mfma_f32_16x16x32_bf16(xa[ks], bkf, ak, 0, 0, 0);
        }
        const float bqv = bq[16 * nt + c16];
        const float bkv = bk[16 * nt + c16];
        #pragma unroll
        for (int r = 0; r < 4; ++r) {
            const int n = n0 + 16 * w + quad * 4 + r;
            const size_t o = ((size_t)b * NTOK + n) * CH + 16 * nt + c16;
            q_ws[o] = f2bf((aq[r] + bqv) * (SCALE * LOG2E));
            k_ws[o] = f2bf(ak[r] + bkv);
        }
    }

    // ---- V (transposed output) ----
    short8 wva[2][4];
    float  bvv[2][4];
    #pragma unroll
    for (int mt = 0; mt < 2; ++mt) {
        const int crow16 = 16 * (2 * w + mt);
        #pragma unroll
        for (int ks = 0; ks < 4; ++ks)
            wva[mt][ks] = *(const short8*)&wvb[(crow16 + c16) * CH + 32 * ks + 8 * quad];
        #pragma unroll
        for (int r = 0; r < 4; ++r)
            bvv[mt][r] = bv[crow16 + quad * 4 + r];
    }
    #pragma unroll
    for (int nt = 0; nt < 4; ++nt) {
        short8 xbf[4];
        #pragma unroll
        for (int ks = 0; ks < 4; ++ks)
            xbf[ks] = *(const short8*)&XsT[(16 * nt + c16) * CH + (((4 * ks + quad) ^ c16) << 3)];
        #pragma unroll
        for (int mt = 0; mt < 2; ++mt) {
            f32x4 acc = (f32x4){0.f, 0.f, 0.f, 0.f};
            #pragma unroll
            for (int ks = 0; ks < 4; ++ks)
                acc = __builtin_amdgcn_mfma_f32_16x16x32_bf16(wva[mt][ks], xbf[ks], acc, 0, 0, 0);
            #pragma unroll
            for (int r = 0; r < 4; ++r) {
                const int crow = 16 * (2 * w + mt) + quad * 4 + r;
                vt_ws[((size_t)b * CH + crow) * NTOK + n0 + 16 * nt + c16] =
                    f2bf(acc[r] + bvv[mt][r]);
            }
        }
    }
}

// ---------------- split-KV MFMA flash attention, in-register P -------------
// block = 256 thr = 4 waves; wave (qhw,chw) = q rows [64*qhw,+64) x ch [64*chw,+64).
// Each wave: 2 q-sets of 32 rows -> every LDS fragment read feeds 2 MFMAs.
template <int SPLIT>
__global__ __launch_bounds__(256, 2) void flash_attn_mfma(
    const unsigned short* __restrict__ q_ws,
    const unsigned short* __restrict__ k_ws,
    const unsigned short* __restrict__ vt_ws,
    float* __restrict__ out,
    float* __restrict__ Op, float* __restrict__ l_p)
{
    __shared__ __align__(16) unsigned short KsU[2][TK * CH];  // 2 x 16 KB
    __shared__ __align__(16) unsigned short VtU[2][CH * TK];  // 2 x 16 KB

    const int t    = threadIdx.x;
    const int w    = t >> 6;
    const int lane = t & 63;
    const int half = lane >> 5;
    const int l32  = lane & 31;
    const int qhw  = w >> 1;   // q 64-row group
    const int chw  = w & 1;    // channel 64-group
    const int jc   = blockIdx.y;
    const int b    = blockIdx.z;
    const int n0   = blockIdx.x * 128;
    const int jbeg = jc * (NTOK / SPLIT);
    constexpr int NT = (NTOK / SPLIT) / TK;

    const unsigned short* kg = k_ws  + (size_t)b * NTOK * CH;
    const unsigned short* vg = vt_ws + (size_t)b * CH * NTOK;

    // Q B-frags for 2 q-sets: B[k=ch][n=q=l32], ch chunk = 16ks+8*half+j
    short8 qa[2][8];
    #pragma unroll
    for (int qs = 0; qs < 2; ++qs) {
        const unsigned short* qrow =
            q_ws + ((size_t)b * NTOK + n0 + 64 * qhw + 32 * qs + l32) * CH;
        #pragma unroll
        for (int ks = 0; ks < 8; ++ks)
            qa[qs][ks] = *(const short8*)(qrow + ks * 16 + half * 8);
    }

    f32x16 Oa[2][2];  // [qs][ct] : O^T tiles, D[m=ch][n=q]
    #pragma unroll
    for (int qs = 0; qs < 2; ++qs)
        #pragma unroll
        for (int ct = 0; ct < 2; ++ct) Oa[qs][ct] = (f32x16)(0.0f);
    float lsum[2] = {0.f, 0.f};

    const int krl = lane >> 4, ku = lane & 15;
    const int vcl = lane >> 3, vu = lane & 7;

    auto STAGE = [&](int buf, int jj) {
        // K rows 16w..16w+15 (XOR-swizzled source, linear LDS dest)
        #pragma unroll
        for (int ci = 0; ci < 4; ++ci) {
            const int row = 16 * w + 4 * ci + krl;
            const int g   = ku ^ (row & 15);
            const unsigned short* src = kg + (size_t)(jj + row) * CH + g * 8;
            __builtin_amdgcn_global_load_lds(
                (const __attribute__((address_space(1))) void*)src,
                (__attribute__((address_space(3))) void*)&KsU[buf][(16 * w + 4 * ci) * CH],
                16, 0, 0);
        }
        // V^T channel rows 32w..32w+31
        #pragma unroll
        for (int ci = 0; ci < 4; ++ci) {
            const int c = 32 * w + 8 * ci + vcl;
            const int g = vu ^ (c & 7);
            const unsigned short* src = vg + (size_t)c * NTOK + jj + g * 8;
            __builtin_amdgcn_global_load_lds(
                (const __attribute__((address_space(1))) void*)src,
                (__attribute__((address_space(3))) void*)&VtU[buf][(32 * w + 8 * ci) * TK],
                16, 0, 0);
        }
    };

    STAGE(0, jbeg);   // 8 loads/wave in flight

    int j0 = jbeg;
    for (int tt = 0; tt < NT; ++tt, j0 += TK) {
        const int cur = tt & 1;
        if (tt + 1 < NT) {
            STAGE(cur ^ 1, j0 + TK);                       // prefetch next tile
            asm volatile("s_waitcnt vmcnt(8)" ::: "memory"); // own cur-loads done
        } else {
            asm volatile("s_waitcnt vmcnt(0)" ::: "memory");
        }
        __builtin_amdgcn_sched_barrier(0);
        __builtin_amdgcn_s_barrier();                      // all waves' cur landed
        __builtin_amdgcn_sched_barrier(0);

        const unsigned short* Kc = &KsU[cur][0];
        const unsigned short* Vc = &VtU[cur][0];

        // --- S^T = K Q^T - MFIX : D[m=ktok][n=q] ; lane holds q=l32 ---
        f32x16 s[2][2];  // [qs][kt]
        #pragma unroll
        for (int qs = 0; qs < 2; ++qs)
            #pragma unroll
            for (int kt = 0; kt < 2; ++kt) s[qs][kt] = (f32x16)(-MFIX);

        #pragma unroll
        for (int ks = 0; ks < 8; ++ks) {
            const int ph = (2 * ks + half) ^ (l32 & 15);
            const short8 kf0 = *(const short8*)&Kc[l32 * CH + ph * 8];
            const short8 kf1 = *(const short8*)&Kc[(32 + l32) * CH + ph * 8];
            s[0][0] = __builtin_amdgcn_mfma_f32_32x32x16_bf16(kf0, qa[0][ks], s[0][0], 0, 0, 0);
            s[1][0] = __builtin_amdgcn_mfma_f32_32x32x16_bf16(kf0, qa[1][ks], s[1][0], 0, 0, 0);
            s[0][1] = __builtin_amdgcn_mfma_f32_32x32x16_bf16(kf1, qa[0][ks], s[0][1], 0, 0, 0);
            s[1][1] = __builtin_amdgcn_mfma_f32_32x32x16_bf16(kf1, qa[1][ks], s[1][1], 0, 0, 0);
        }

        // --- P = exp2(S) in-register; pack to PV B-frags via cvt_pk+permlane ---
        short8 pb[2][4];  // [qs][ks2] : B[k=16ks2+8h+j][n=q]
        #pragma unroll
        for (int qs = 0; qs < 2; ++qs) {
            #pragma unroll
            for (int kt = 0; kt < 2; ++kt) {
                float p[16];
                #pragma unroll
                for (int r = 0; r < 16; ++r) p[r] = exp2f(s[qs][kt][r]);
                float a0 = 0.f, a1 = 0.f, a2 = 0.f, a3 = 0.f;
                #pragma unroll
                for (int r = 0; r < 4; ++r) {
                    a0 += p[r]; a1 += p[4 + r]; a2 += p[8 + r]; a3 += p[12 + r];
                }
                lsum[qs] += (a0 + a1) + (a2 + a3);
                unsigned wd[8];
                #pragma unroll
                for (int i = 0; i < 8; ++i) wd[i] = cvt_pk_bf16(p[2 * i], p[2 * i + 1]);
                auto r02 = __builtin_amdgcn_permlane32_swap(wd[0], wd[2], false, false);
                auto r13 = __builtin_amdgcn_permlane32_swap(wd[1], wd[3], false, false);
                auto r46 = __builtin_amdgcn_permlane32_swap(wd[4], wd[6], false, false);
                auto r57 = __builtin_amdgcn_permlane32_swap(wd[5], wd[7], false, false);
                union { unsigned u[4]; short8 s8; } f0, f1;
                f0.u[0] = r02[0]; f0.u[1] = r13[0]; f0.u[2] = r02[1]; f0.u[3] = r13[1];
                f1.u[0] = r46[0]; f1.u[1] = r57[0]; f1.u[2] = r46[1]; f1.u[3] = r57[1];
                pb[qs][2 * kt + 0] = f0.s8;
                pb[qs][2 * kt + 1] = f1.s8;
            }
        }

        // --- O^T += V^T P^T : each vf read feeds both q-sets ---
        #pragma unroll
        for (int ks2 = 0; ks2 < 4; ++ks2) {
            #pragma unroll
            for (int ct = 0; ct < 2; ++ct) {
                const int ch = 64 * chw + 32 * ct + l32;
                const int ph = (2 * ks2 + half) ^ (ch & 7);
                const short8 vf = *(const short8*)&Vc[ch * TK + ph * 8];
                Oa[0][ct] = __builtin_amdgcn_mfma_f32_32x32x16_bf16(vf, pb[0][ks2], Oa[0][ct], 0, 0, 0);
                Oa[1][ct] = __builtin_amdgcn_mfma_f32_32x32x16_bf16(vf, pb[1][ks2], Oa[1][ct], 0, 0, 0);
            }
        }
        __builtin_amdgcn_sched_barrier(0);
        __builtin_amdgcn_s_barrier();   // all waves done reading cur before re-stage
        __builtin_amdgcn_sched_barrier(0);
    }

    // --- epilogue: l lane-local; stores coalesced (lane = token) ---
    float lt[2];
    #pragma unroll
    for (int qs = 0; qs < 2; ++qs)
        lt[qs] = lsum[qs] + __shfl_xor(lsum[qs], 32);

    if constexpr (SPLIT == 1) {
        #pragma unroll
        for (int qs = 0; qs < 2; ++qs) {
            const float inv = 1.0f / lt[qs];
            const int n = n0 + 64 * qhw + 32 * qs + l32;
            #pragma unroll
            for (int ct = 0; ct < 2; ++ct) {
                #pragma unroll
                for (int r = 0; r < 16; ++r) {
                    const int c = 64 * chw + 32 * ct + (r & 3) + 8 * (r >> 2) + 4 * half;
                    out[((size_t)b * CH + c) * NTOK + n] = Oa[qs][ct][r] * inv;
                }
            }
        }
    } else {
        const size_t chunk = (size_t)(b * SPLIT + jc);
        #pragma unroll
        for (int qs = 0; qs < 2; ++qs) {
            const int n = n0 + 64 * qhw + 32 * qs + l32;
            #pragma unroll
            for (int ct = 0; ct < 2; ++ct) {
                #pragma unroll
                for (int r = 0; r < 16; ++r) {
                    const int c = 64 * chw + 32 * ct + (r & 3) + 8 * (r >> 2) + 4 * half;
                    Op[(chunk * CH + c) * NTOK + n] = Oa[qs][ct][r];
                }
            }
            if (chw == 0 && half == 0)
                l_p[chunk * NTOK + n] = lt[qs];
        }
    }
}

// ---------------- combine partials: Op layout [chunk][C][N], coalesced -----
template <int SPLIT>
__global__ __launch_bounds__(256) void combine_kernel(
    const float* __restrict__ Op, const float* __restrict__ l_p,
    float* __restrict__ out)
{
    const int b = blockIdx.y;
    const size_t idx = ((size_t)blockIdx.x * 256 + threadIdx.x) * 4;  // in C*N
    const int c = (int)(idx >> 12);           // / NTOK
    const int n = (int)(idx & (NTOK - 1));
    float4 acc = make_float4(0.f, 0.f, 0.f, 0.f);
    float4 den = make_float4(0.f, 0.f, 0.f, 0.f);
    #pragma unroll
    for (int j = 0; j < SPLIT; ++j) {
        const size_t chunk = (size_t)(b * SPLIT + j);
        const float4 o = *(const float4*)&Op[(chunk * CH + c) * NTOK + n];
        const float4 d = *(const float4*)&l_p[chunk * NTOK + n];
        acc.x += o.x; acc.y += o.y; acc.z += o.z; acc.w += o.w;
        den.x += d.x; den.y += d.y; den.z += d.z; den.w += d.w;
    }
    float4 r;
    r.x = acc.x / den.x; r.y = acc.y / den.y;
    r.z = acc.z / den.z; r.w = acc.w / den.w;
    *(float4*)&out[((size_t)b * CH * NTOK) + idx] = r;
}

extern "C" void kernel_launch(void* const* d_in, const int* in_sizes, int n_in,
                              void* d_out, int out_size, void* d_ws, size_t ws_size,
                              hipStream_t stream) {
    const float* x  = (const float*)d_in[0];
    const float* Wq = (const float*)d_in[1];
    const float* bq = (const float*)d_in[2];
    const float* Wk = (const float*)d_in[3];
    const float* bk = (const float*)d_in[4];
    const float* Wv = (const float*)d_in[5];
    const float* bv = (const float*)d_in[6];
    float* out = (float*)d_out;

    const size_t QKV = (size_t)BATCH * NTOK * CH;
    unsigned short* q_ws  = (unsigned short*)d_ws;
    unsigned short* k_ws  = q_ws + QKV;
    unsigned short* vt_ws = k_ws + QKV;
    unsigned short* wb    = vt_ws + QKV;
    float* Op = (float*)(wb + 3 * CH * CH);

    const size_t baseBytes = 3 * QKV * 2 + 3 * CH * CH * 2;
    auto needBytes = [&](size_t S) {
        return baseBytes + S * BATCH * NTOK * (size_t)(CH * 4 + 4);
    };

    convert_w_kernel<<<CH * CH / (256 * 4), 256, 0, stream>>>(Wq, Wk, Wv, wb);

    dim3 gp(NTOK / 64, BATCH);
    proj_mfma_kernel<<<gp, 256, 0, stream>>>(x, wb, wb + CH * CH, wb + 2 * CH * CH,
                                             bq, bk, bv, q_ws, k_ws, vt_ws);

    dim3 gc(CH * NTOK / 1024, BATCH);
    if (ws_size >= needBytes(4)) {
        float* l_p = Op + (size_t)4 * BATCH * NTOK * CH;
        dim3 ga(NTOK / 128, 4, BATCH);
        flash_attn_mfma<4><<<ga, 256, 0, stream>>>(q_ws, k_ws, vt_ws, out, Op, l_p);
        combine_kernel<4><<<gc, 256, 0, stream>>>(Op, l_p, out);
    } else if (ws_size >= needBytes(2)) {
        float* l_p = Op + (size_t)2 * BATCH * NTOK * CH;
        dim3 ga(NTOK / 128, 2, BATCH);
        flash_attn_mfma<2><<<ga, 256, 0, stream>>>(q_ws, k_ws, vt_ws, out, Op, l_p);
        combine_kernel<2><<<gc, 256, 0, stream>>>(Op, l_p, out);
    } else {
        dim3 ga(NTOK / 128, 1, BATCH);
        flash_attn_mfma<1><<<ga, 256, 0, stream>>>(q_ws, k_ws, vt_ws, out,
                                                   nullptr, nullptr);
    }
}

// Round 2
// 132.079 us; speedup vs baseline: 1.3216x; 1.3216x over previous
//
#include <hip/hip_runtime.h>
#include <hip/hip_bf16.h>

// B=4, C=128, H=W=64 -> N=4096. ALL I/O FP32.
// Round 7: round-5 wave structure (32 q-rows/wave, NO duplication) + verified
// in-register softmax (swapped QK^T, cvt_pk+permlane32_swap, O^T PV, lane-local
// l) + counted-vmcnt double-buffered K/V staging. LDS demand = exactly 1
// fragment per MFMA (the CU balance point). proj split over grid.z={Q,K,V}
// (768 blocks, 3/CU) to fix its 1-wave/SIMD latency exposure. SPLIT=4.

#define BATCH 4
#define CH    128
#define NTOK  4096
#define TK    64
#define SCALE 0.08838834764831845f   // 1/sqrt(128)
#define LOG2E 1.4426950408889634f
#define MFIX  16.0f                  // fixed softmax offset (log2 units)

typedef __attribute__((ext_vector_type(8)))  short short8;
typedef __attribute__((ext_vector_type(4)))  float f32x4;
typedef __attribute__((ext_vector_type(16))) float f32x16;

static __device__ __forceinline__ unsigned short f2bf(float f) {
    __hip_bfloat16 h = (__hip_bfloat16)f;
    return *(const unsigned short*)&h;
}

static __device__ __forceinline__ unsigned cvt_pk_bf16(float lo, float hi) {
    unsigned r;
    asm("v_cvt_pk_bf16_f32 %0, %1, %2" : "=v"(r) : "v"(lo), "v"(hi));
    return r;
}

// ---------------- W fp32 -> bf16 ----------------
__global__ __launch_bounds__(256) void convert_w_kernel(
    const float* __restrict__ Wq, const float* __restrict__ Wk,
    const float* __restrict__ Wv, unsigned short* __restrict__ wb)
{
    const int idx = (blockIdx.x * 256 + threadIdx.x) * 4;
    const float* srcs[3] = {Wq, Wk, Wv};
    #pragma unroll
    for (int m = 0; m < 3; ++m) {
        float4 v = *(const float4*)(srcs[m] + idx);
        unsigned short o[4] = {f2bf(v.x), f2bf(v.y), f2bf(v.z), f2bf(v.w)};
        *(uint2*)(wb + (size_t)m * CH * CH + idx) = *(const uint2*)o;
    }
}

// ---------------- MFMA QKV projection, z-split over {Q,K,V} ----------------
// grid (NTOK/64, BATCH, 3), 256 thr. 3 blocks/CU instead of 1 -> latency
// hidden by TLP. x tile staged per block (redundant 3x read, L2/L3-cached).
__global__ __launch_bounds__(256) void proj_mfma_kernel(
    const float* __restrict__ x,
    const unsigned short* __restrict__ wb_all,
    const float* __restrict__ bq, const float* __restrict__ bk,
    const float* __restrict__ bv,
    unsigned short* __restrict__ q_ws, unsigned short* __restrict__ k_ws,
    unsigned short* __restrict__ vt_ws)
{
    __shared__ __align__(16) unsigned short XsT[64 * CH];  // 16 KB, swizzled

    const int t    = threadIdx.x;
    const int w    = t >> 6;
    const int lane = t & 63;
    const int quad = lane >> 4;
    const int c16  = lane & 15;
    const int n0   = blockIdx.x * 64;
    const int b    = blockIdx.y;
    const int z    = blockIdx.z;          // 0=Q, 1=K, 2=V
    const float* xb = x + (size_t)b * CH * NTOK;

    {   // stage: wave w covers channels 32w..32w+31; lane = token.
        const int tok = lane;
        #pragma unroll
        for (int cc = 0; cc < 4; ++cc) {
            const int cb = 32 * w + 8 * cc;
            unsigned short tmp[8];
            #pragma unroll
            for (int j = 0; j < 8; ++j)
                tmp[j] = f2bf(xb[(size_t)(cb + j) * NTOK + n0 + tok]);
            const int phys = ((cb >> 3) ^ (tok & 15));
            *(short8*)&XsT[tok * CH + phys * 8] = *(const short8*)tmp;
        }
    }
    __syncthreads();

    if (z < 2) {
        // ---- Q or K: out[n][c'] = sum_c x[n][c] W[c'][c] + b ----
        const unsigned short* wm = wb_all + (size_t)z * CH * CH;
        const float* bias = (z == 0) ? bq : bk;
        unsigned short* dst = (z == 0) ? q_ws : k_ws;
        const float mul = (z == 0) ? (SCALE * LOG2E) : 1.0f;

        short8 xa[4];
        #pragma unroll
        for (int ks = 0; ks < 4; ++ks)
            xa[ks] = *(const short8*)&XsT[(16 * w + c16) * CH + (((4 * ks + quad) ^ c16) << 3)];

        #pragma unroll
        for (int nt = 0; nt < 8; ++nt) {
            f32x4 a = (f32x4){0.f, 0.f, 0.f, 0.f};
            const unsigned short* wr = wm + (16 * nt + c16) * CH;
            #pragma unroll
            for (int ks = 0; ks < 4; ++ks) {
                const short8 bf = *(const short8*)(wr + 32 * ks + 8 * quad);
                a = __builtin_amdgcn_mfma_f32_16x16x32_bf16(xa[ks], bf, a, 0, 0, 0);
            }
            const float bvv = bias[16 * nt + c16];
            #pragma unroll
            for (int r = 0; r < 4; ++r) {
                const int n = n0 + 16 * w + quad * 4 + r;
                dst[((size_t)b * NTOK + n) * CH + 16 * nt + c16] =
                    f2bf((a[r] + bvv) * mul);
            }
        }
    } else {
        // ---- V (transposed output vt[c][n]) ----
        const unsigned short* wvb = wb_all + (size_t)2 * CH * CH;
        short8 wva[2][4];
        float  bvv[2][4];
        #pragma unroll
        for (int mt = 0; mt < 2; ++mt) {
            const int crow16 = 16 * (2 * w + mt);
            #pragma unroll
            for (int ks = 0; ks < 4; ++ks)
                wva[mt][ks] = *(const short8*)&wvb[(crow16 + c16) * CH + 32 * ks + 8 * quad];
            #pragma unroll
            for (int r = 0; r < 4; ++r)
                bvv[mt][r] = bv[crow16 + quad * 4 + r];
        }
        #pragma unroll
        for (int nt = 0; nt < 4; ++nt) {
            short8 xbf[4];
            #pragma unroll
            for (int ks = 0; ks < 4; ++ks)
                xbf[ks] = *(const short8*)&XsT[(16 * nt + c16) * CH + (((4 * ks + quad) ^ c16) << 3)];
            #pragma unroll
            for (int mt = 0; mt < 2; ++mt) {
                f32x4 acc = (f32x4){0.f, 0.f, 0.f, 0.f};
                #pragma unroll
                for (int ks = 0; ks < 4; ++ks)
                    acc = __builtin_amdgcn_mfma_f32_16x16x32_bf16(wva[mt][ks], xbf[ks], acc, 0, 0, 0);
                #pragma unroll
                for (int r = 0; r < 4; ++r) {
                    const int crow = 16 * (2 * w + mt) + quad * 4 + r;
                    vt_ws[((size_t)b * CH + crow) * NTOK + n0 + 16 * nt + c16] =
                        f2bf(acc[r] + bvv[mt][r]);
                }
            }
        }
    }
}

// ---------------- split-KV MFMA flash attention, in-register P -------------
// block = 256 thr = 4 waves; wave w owns q rows n0+32w..+31, ALL 128 channels.
// Per wave-tile: 16 QK^T MFMA + 16 PV MFMA, 32 LDS b128 reads (1 frag/MFMA).
template <int SPLIT>
__global__ __launch_bounds__(256, 2) void flash_attn_mfma(
    const unsigned short* __restrict__ q_ws,
    const unsigned short* __restrict__ k_ws,
    const unsigned short* __restrict__ vt_ws,
    float* __restrict__ out,
    float* __restrict__ Op, float* __restrict__ l_p)
{
    __shared__ __align__(16) unsigned short KsU[2][TK * CH];  // 2 x 16 KB
    __shared__ __align__(16) unsigned short VtU[2][CH * TK];  // 2 x 16 KB

    const int t    = threadIdx.x;
    const int w    = t >> 6;
    const int lane = t & 63;
    const int half = lane >> 5;
    const int l32  = lane & 31;
    const int jc   = blockIdx.y;
    const int b    = blockIdx.z;
    const int n0   = blockIdx.x * 128;
    const int jbeg = jc * (NTOK / SPLIT);
    constexpr int NT = (NTOK / SPLIT) / TK;

    const unsigned short* kg = k_ws  + (size_t)b * NTOK * CH;
    const unsigned short* vg = vt_ws + (size_t)b * CH * NTOK;

    // Q B-frags: B[k=ch][n=q=l32], ch chunk = 16ks+8*half+j
    short8 qa[8];
    {
        const unsigned short* qrow =
            q_ws + ((size_t)b * NTOK + n0 + 32 * w + l32) * CH;
        #pragma unroll
        for (int ks = 0; ks < 8; ++ks)
            qa[ks] = *(const short8*)(qrow + ks * 16 + half * 8);
    }

    f32x16 Oa[4];  // O^T tiles, D[m=ch 32ct..][n=q]
    #pragma unroll
    for (int ct = 0; ct < 4; ++ct) Oa[ct] = (f32x16)(0.0f);
    float lsum = 0.f;

    const int krl = lane >> 4, ku = lane & 15;
    const int vcl = lane >> 3, vu = lane & 7;

    auto STAGE = [&](int buf, int jj) {
        // K rows 16w..16w+15 (XOR-swizzled source, linear LDS dest)
        #pragma unroll
        for (int ci = 0; ci < 4; ++ci) {
            const int row = 16 * w + 4 * ci + krl;
            const int g   = ku ^ (row & 15);
            const unsigned short* src = kg + (size_t)(jj + row) * CH + g * 8;
            __builtin_amdgcn_global_load_lds(
                (const __attribute__((address_space(1))) void*)src,
                (__attribute__((address_space(3))) void*)&KsU[buf][(16 * w + 4 * ci) * CH],
                16, 0, 0);
        }
        // V^T channel rows 32w..32w+31
        #pragma unroll
        for (int ci = 0; ci < 4; ++ci) {
            const int c = 32 * w + 8 * ci + vcl;
            const int g = vu ^ (c & 7);
            const unsigned short* src = vg + (size_t)c * NTOK + jj + g * 8;
            __builtin_amdgcn_global_load_lds(
                (const __attribute__((address_space(1))) void*)src,
                (__attribute__((address_space(3))) void*)&VtU[buf][(32 * w + 8 * ci) * TK],
                16, 0, 0);
        }
    };

    STAGE(0, jbeg);   // 8 loads/wave in flight

    int j0 = jbeg;
    for (int tt = 0; tt < NT; ++tt, j0 += TK) {
        const int cur = tt & 1;
        if (tt + 1 < NT) {
            STAGE(cur ^ 1, j0 + TK);                         // prefetch next
            asm volatile("s_waitcnt vmcnt(8)" ::: "memory"); // own cur loads done
        } else {
            asm volatile("s_waitcnt vmcnt(0)" ::: "memory");
        }
        __builtin_amdgcn_sched_barrier(0);
        __builtin_amdgcn_s_barrier();                        // all waves' cur landed
        __builtin_amdgcn_sched_barrier(0);

        const unsigned short* Kc = &KsU[cur][0];
        const unsigned short* Vc = &VtU[cur][0];

        // --- S^T = K Q^T - MFIX : D[m=ktok][n=q] ; lane holds q=l32 ---
        f32x16 s[2];
        s[0] = (f32x16)(-MFIX);
        s[1] = (f32x16)(-MFIX);
        #pragma unroll
        for (int ks = 0; ks < 8; ++ks) {
            const int ph = (2 * ks + half) ^ (l32 & 15);
            const short8 kf0 = *(const short8*)&Kc[l32 * CH + ph * 8];
            const short8 kf1 = *(const short8*)&Kc[(32 + l32) * CH + ph * 8];
            s[0] = __builtin_amdgcn_mfma_f32_32x32x16_bf16(kf0, qa[ks], s[0], 0, 0, 0);
            s[1] = __builtin_amdgcn_mfma_f32_32x32x16_bf16(kf1, qa[ks], s[1], 0, 0, 0);
        }

        // --- P = exp2(S) in-register; pack to PV B-frags via cvt_pk+permlane ---
        short8 pb[4];  // B[k=16ks2+8h+j][n=q]
        #pragma unroll
        for (int kt = 0; kt < 2; ++kt) {
            float p[16];
            #pragma unroll
            for (int r = 0; r < 16; ++r) p[r] = exp2f(s[kt][r]);
            float a0 = 0.f, a1 = 0.f, a2 = 0.f, a3 = 0.f;
            #pragma unroll
            for (int r = 0; r < 4; ++r) {
                a0 += p[r]; a1 += p[4 + r]; a2 += p[8 + r]; a3 += p[12 + r];
            }
            lsum += (a0 + a1) + (a2 + a3);
            unsigned wd[8];
            #pragma unroll
            for (int i = 0; i < 8; ++i) wd[i] = cvt_pk_bf16(p[2 * i], p[2 * i + 1]);
            auto r02 = __builtin_amdgcn_permlane32_swap(wd[0], wd[2], false, false);
            auto r13 = __builtin_amdgcn_permlane32_swap(wd[1], wd[3], false, false);
            auto r46 = __builtin_amdgcn_permlane32_swap(wd[4], wd[6], false, false);
            auto r57 = __builtin_amdgcn_permlane32_swap(wd[5], wd[7], false, false);
            union { unsigned u[4]; short8 s8; } f0, f1;
            f0.u[0] = r02[0]; f0.u[1] = r13[0]; f0.u[2] = r02[1]; f0.u[3] = r13[1];
            f1.u[0] = r46[0]; f1.u[1] = r57[0]; f1.u[2] = r46[1]; f1.u[3] = r57[1];
            pb[2 * kt + 0] = f0.s8;
            pb[2 * kt + 1] = f1.s8;
        }

        // --- O^T += V^T P^T ---
        #pragma unroll
        for (int ks2 = 0; ks2 < 4; ++ks2) {
            #pragma unroll
            for (int ct = 0; ct < 4; ++ct) {
                const int ch = 32 * ct + l32;
                const int ph = (2 * ks2 + half) ^ (ch & 7);
                const short8 vf = *(const short8*)&Vc[ch * TK + ph * 8];
                Oa[ct] = __builtin_amdgcn_mfma_f32_32x32x16_bf16(vf, pb[ks2], Oa[ct], 0, 0, 0);
            }
        }
        __builtin_amdgcn_sched_barrier(0);
        __builtin_amdgcn_s_barrier();   // all waves done reading cur before re-stage
        __builtin_amdgcn_sched_barrier(0);
    }

    // --- epilogue: l lane-local; stores coalesced (lane = token) ---
    const float lt = lsum + __shfl_xor(lsum, 32);
    const int n = n0 + 32 * w + l32;

    if constexpr (SPLIT == 1) {
        const float inv = 1.0f / lt;
        #pragma unroll
        for (int ct = 0; ct < 4; ++ct) {
            #pragma unroll
            for (int r = 0; r < 16; ++r) {
                const int c = 32 * ct + (r & 3) + 8 * (r >> 2) + 4 * half;
                out[((size_t)b * CH + c) * NTOK + n] = Oa[ct][r] * inv;
            }
        }
    } else {
        const size_t chunk = (size_t)(b * SPLIT + jc);
        #pragma unroll
        for (int ct = 0; ct < 4; ++ct) {
            #pragma unroll
            for (int r = 0; r < 16; ++r) {
                const int c = 32 * ct + (r & 3) + 8 * (r >> 2) + 4 * half;
                Op[(chunk * CH + c) * NTOK + n] = Oa[ct][r];
            }
        }
        if (half == 0) l_p[chunk * NTOK + n] = lt;
    }
}

// ---------------- combine partials: Op layout [chunk][C][N], coalesced -----
template <int SPLIT>
__global__ __launch_bounds__(256) void combine_kernel(
    const float* __restrict__ Op, const float* __restrict__ l_p,
    float* __restrict__ out)
{
    const int b = blockIdx.y;
    const size_t idx = ((size_t)blockIdx.x * 256 + threadIdx.x) * 4;  // in C*N
    const int c = (int)(idx >> 12);           // / NTOK
    const int n = (int)(idx & (NTOK - 1));
    float4 acc = make_float4(0.f, 0.f, 0.f, 0.f);
    float4 den = make_float4(0.f, 0.f, 0.f, 0.f);
    #pragma unroll
    for (int j = 0; j < SPLIT; ++j) {
        const size_t chunk = (size_t)(b * SPLIT + j);
        const float4 o = *(const float4*)&Op[(chunk * CH + c) * NTOK + n];
        const float4 d = *(const float4*)&l_p[chunk * NTOK + n];
        acc.x += o.x; acc.y += o.y; acc.z += o.z; acc.w += o.w;
        den.x += d.x; den.y += d.y; den.z += d.z; den.w += d.w;
    }
    float4 r;
    r.x = acc.x / den.x; r.y = acc.y / den.y;
    r.z = acc.z / den.z; r.w = acc.w / den.w;
    *(float4*)&out[((size_t)b * CH * NTOK) + idx] = r;
}

extern "C" void kernel_launch(void* const* d_in, const int* in_sizes, int n_in,
                              void* d_out, int out_size, void* d_ws, size_t ws_size,
                              hipStream_t stream) {
    const float* x  = (const float*)d_in[0];
    const float* Wq = (const float*)d_in[1];
    const float* bq = (const float*)d_in[2];
    const float* Wk = (const float*)d_in[3];
    const float* bk = (const float*)d_in[4];
    const float* Wv = (const float*)d_in[5];
    const float* bv = (const float*)d_in[6];
    float* out = (float*)d_out;

    const size_t QKV = (size_t)BATCH * NTOK * CH;
    unsigned short* q_ws  = (unsigned short*)d_ws;
    unsigned short* k_ws  = q_ws + QKV;
    unsigned short* vt_ws = k_ws + QKV;
    unsigned short* wb    = vt_ws + QKV;
    float* Op = (float*)(wb + 3 * CH * CH);

    const size_t baseBytes = 3 * QKV * 2 + 3 * CH * CH * 2;
    auto needBytes = [&](size_t S) {
        return baseBytes + S * BATCH * NTOK * (size_t)(CH * 4 + 4);
    };

    convert_w_kernel<<<CH * CH / (256 * 4), 256, 0, stream>>>(Wq, Wk, Wv, wb);

    dim3 gp(NTOK / 64, BATCH, 3);
    proj_mfma_kernel<<<gp, 256, 0, stream>>>(x, wb, bq, bk, bv, q_ws, k_ws, vt_ws);

    dim3 gc(CH * NTOK / 1024, BATCH);
    if (ws_size >= needBytes(4)) {
        float* l_p = Op + (size_t)4 * BATCH * NTOK * CH;
        dim3 ga(NTOK / 128, 4, BATCH);
        flash_attn_mfma<4><<<ga, 256, 0, stream>>>(q_ws, k_ws, vt_ws, out, Op, l_p);
        combine_kernel<4><<<gc, 256, 0, stream>>>(Op, l_p, out);
    } else if (ws_size >= needBytes(2)) {
        float* l_p = Op + (size_t)2 * BATCH * NTOK * CH;
        dim3 ga(NTOK / 128, 2, BATCH);
        flash_attn_mfma<2><<<ga, 256, 0, stream>>>(q_ws, k_ws, vt_ws, out, Op, l_p);
        combine_kernel<2><<<gc, 256, 0, stream>>>(Op, l_p, out);
    } else {
        dim3 ga(NTOK / 128, 1, BATCH);
        flash_attn_mfma<1><<<ga, 256, 0, stream>>>(q_ws, k_ws, vt_ws, out,
                                                   nullptr, nullptr);
    }
}